// Round 1
// baseline (131.283 us; speedup 1.0000x reference)
//
#include <hip/hip_runtime.h>

// Problem constants (from setup_inputs): B=2, N=M=2048, T=3 flow types.
#define TT 3
#define BB 2
#define NN 2048
#define MM 2048

// ---------------------------------------------------------------------------
// Kernel 1: brute-force nearest-neighbor chamfer + opposite-flow loss.
// Grid: 2(dir) * T * B * (N/64) = 384 blocks, 256 threads.
// Thread layout: si = tid&63 (source point within chunk), j = tid>>6 (target
// chunk of 512). Targets staged in LDS as float4 for broadcast ds_read_b128.
// Each block contributes one atomicAdd of its weighted partial sum.
// ---------------------------------------------------------------------------
__global__ __launch_bounds__(256) void knn_kernel(
    const float* __restrict__ pc0, const float* __restrict__ pc1,
    const float* __restrict__ flows_fw, const float* __restrict__ flows_bw,
    float* __restrict__ out)
{
    __shared__ float4 s_tgt[MM];     // 32 KB
    __shared__ float  s_bd[256];
    __shared__ int    s_bi[256];

    int bid   = blockIdx.x;
    int chunk = bid & 31;            // N/64 = 32 chunks
    int rest  = bid >> 5;
    int b     = rest & 1;            // B = 2
    rest    >>= 1;
    int t     = rest % 3;
    int dir   = rest / 3;            // 0 = fw (src=pc0,tgt=pc1), 1 = bw

    const float* pc_src = dir ? pc1 : pc0;
    const float* pc_tgt = dir ? pc0 : pc1;
    const float* fl_src = dir ? flows_bw : flows_fw;
    const float* fl_tgt = dir ? flows_fw : flows_bw;

    int tid = threadIdx.x;

    // Stage target cloud for this b into LDS (coalesced-ish scalar reads).
    for (int p = tid; p < MM; p += 256) {
        const float* q = pc_tgt + ((size_t)b * MM + p) * 3;
        s_tgt[p] = make_float4(q[0], q[1], q[2], 0.f);
    }
    __syncthreads();

    int si = tid & 63;
    int j  = tid >> 6;
    int n  = chunk * 64 + si;

    const float* fs = fl_src + (((size_t)t * BB + b) * NN + n) * 3;
    const float* ps = pc_src + ((size_t)b * NN + n) * 3;
    float fx = fs[0], fy = fs[1], fz = fs[2];
    float wx = ps[0] + fx, wy = ps[1] + fy, wz = ps[2] + fz;

    float bd = 3.402823466e38f;
    int   bi = 0;
    int m0 = j * (MM / 4), m1 = m0 + (MM / 4);
    for (int m = m0; m < m1; ++m) {
        float4 tp = s_tgt[m];
        float dx = wx - tp.x, dy = wy - tp.y, dz = wz - tp.z;
        float d2 = dx * dx + dy * dy + dz * dz;
        if (d2 < bd) { bd = d2; bi = m; }   // strict < : first-occurrence argmin
    }
    s_bd[tid] = bd;
    s_bi[tid] = bi;
    __syncthreads();

    if (tid < 64) {   // exactly wave 0; these threads had j==0 (same n, fx/fy/fz valid)
        float best = s_bd[tid];
        int   bix  = s_bi[tid];
        #pragma unroll
        for (int jj = 1; jj < 4; ++jj) {   // ascending chunk order keeps lowest index on ties
            float d  = s_bd[jj * 64 + tid];
            int   ii = s_bi[jj * 64 + tid];
            if (d < best) { best = d; bix = ii; }
        }
        // partner flow gather (scattered 12B global read, L2-resident)
        const float* pf = fl_tgt + (((size_t)t * BB + b) * MM + bix) * 3;
        float ox = fx + pf[0], oy = fy + pf[1], oz = fz + pf[2];

        const float scale = 0.5f / (BB * NN);
        float wnd = scale * (t == 0 ? 1.0f : 0.5f);   // KNN_PEN=1, DYN_PEN=STAT_PEN=0.5
        float wop = (t == 0 ? scale : 0.0f);          // OPP_PEN=1, t==0 only
        float contrib = wnd * best + wop * (ox * ox + oy * oy + oz * oz);

        #pragma unroll
        for (int off = 32; off; off >>= 1)
            contrib += __shfl_down(contrib, off, 64);
        if (tid == 0) atomicAdd(out, contrib);
    }
}

// ---------------------------------------------------------------------------
// Kernel 2: occlusion + static-flow + trafo-cycle losses. Single block of 256.
// Runs FIRST and plain-stores out[0], providing the zero-init for kernel 1's
// atomics (d_out is re-poisoned to 0xAA before every launch).
// ---------------------------------------------------------------------------
__global__ __launch_bounds__(256) void aux_kernel(
    const float* __restrict__ pc0, const float* __restrict__ pc1,
    const float* __restrict__ flows_fw, const float* __restrict__ flows_bw,
    const float* __restrict__ disap_fw, const float* __restrict__ disap_bw,
    const float* __restrict__ trafo_fw, const float* __restrict__ trafo_bw,
    const float* __restrict__ stat_fw, const float* __restrict__ stat_bw,
    float* __restrict__ out)
{
    __shared__ float s_tf[32], s_tb[32];
    __shared__ float s_red[4];
    int tid = threadIdx.x;
    if (tid < 32) { s_tf[tid] = trafo_fw[tid]; s_tb[tid] = trafo_bw[tid]; }
    __syncthreads();

    const float occl_w = 0.1f * 0.5f / (BB * NN);   // OCCL_PEN * 0.5 / (B*N)
    const float sf_w   = 1.0f * 0.5f / (BB * NN);   // STATIC_FLOW_PEN * 0.5 / (B*N)

    float acc = 0.f;
    for (int idx = tid; idx < 2 * BB * NN; idx += 256) {
        int dir = idx >> 12;                 // 0: fw, 1: bw  (B*N = 4096)
        int r   = idx & (BB * NN - 1);       // b*N + n
        const float* disap = dir ? disap_bw : disap_fw;
        const float* pc    = dir ? pc1 : pc0;
        const float* fl    = (dir ? flows_bw : flows_fw) + (((size_t)2 * BB) * NN) * 3 + (size_t)r * 3;
        const float* st    = dir ? stat_bw : stat_fw;
        const float* Tm    = dir ? s_tb : s_tf;
        int b = r >> 11;

        acc += occl_w * disap[r];

        float x = pc[r * 3 + 0], y = pc[r * 3 + 1], z = pc[r * 3 + 2];
        const float* Tb = Tm + b * 16;
        float i0 = Tb[0] * x + Tb[1] * y + Tb[2]  * z + Tb[3]  - x;
        float i1 = Tb[4] * x + Tb[5] * y + Tb[6]  * z + Tb[7]  - y;
        float i2 = Tb[8] * x + Tb[9] * y + Tb[10] * z + Tb[11] - z;
        float d0 = fl[0] - i0, d1 = fl[1] - i1, d2v = fl[2] - i2;
        acc += sf_w * st[r] * (d0 * d0 + d1 * d1 + d2v * d2v);
    }

    // trafo cycle loss: mean_b || T_fw @ T_bw - I ||_F^2   (32 = B*16 entries)
    if (tid < 32) {
        int b = tid >> 4, i = (tid >> 2) & 3, k = tid & 3;
        float v = 0.f;
        #pragma unroll
        for (int jj = 0; jj < 4; ++jj)
            v += s_tf[b * 16 + i * 4 + jj] * s_tb[b * 16 + jj * 4 + k];
        v -= (i == k) ? 1.f : 0.f;
        acc += v * v * (1.0f / BB);          // TRAFO_PEN=1, mean over B
    }

    #pragma unroll
    for (int off = 32; off; off >>= 1)
        acc += __shfl_down(acc, off, 64);
    if ((tid & 63) == 0) s_red[tid >> 6] = acc;
    __syncthreads();
    if (tid == 0) out[0] = s_red[0] + s_red[1] + s_red[2] + s_red[3];
}

extern "C" void kernel_launch(void* const* d_in, const int* in_sizes, int n_in,
                              void* d_out, int out_size, void* d_ws, size_t ws_size,
                              hipStream_t stream) {
    const float* pc0      = (const float*)d_in[0];
    const float* pc1      = (const float*)d_in[1];
    const float* flows_fw = (const float*)d_in[2];
    const float* flows_bw = (const float*)d_in[3];
    const float* disap_fw = (const float*)d_in[4];
    const float* disap_bw = (const float*)d_in[5];
    const float* trafo_fw = (const float*)d_in[6];
    const float* trafo_bw = (const float*)d_in[7];
    const float* stat_fw  = (const float*)d_in[8];
    const float* stat_bw  = (const float*)d_in[9];
    float* out = (float*)d_out;

    // aux first: it WRITES out[0] (init for knn's atomicAdds; stream order
    // guarantees it completes before knn_kernel starts).
    aux_kernel<<<1, 256, 0, stream>>>(pc0, pc1, flows_fw, flows_bw,
                                      disap_fw, disap_bw, trafo_fw, trafo_bw,
                                      stat_fw, stat_bw, out);

    int nblocks = 2 * TT * BB * (NN / 64);   // 384
    knn_kernel<<<nblocks, 256, 0, stream>>>(pc0, pc1, flows_fw, flows_bw, out);
}

// Round 2
// 92.166 us; speedup vs baseline: 1.4244x; 1.4244x over previous
//
#include <hip/hip_runtime.h>

// Problem constants: B=2, N=M=2048, T=3 flow types.
#define TT 3
#define BB 2
#define NN 2048
#define MM 2048
#define KNN_BLOCKS 384   // 2(dir) * 3(t) * 2(b) * 32 chunks of 64 src points
#define AUX_BLOCKS 16
#define INFF 3.402823466e38f

// ---------------------------------------------------------------------------
// Fused kernel. Blocks [0,384): brute-force NN chamfer + opposite-flow loss.
//   Thread layout: si = tid&31 -> source points (si, si+32); j = tid>>5 ->
//   target chunk of 256. Per wave: 2 distinct LDS broadcast addrs (free).
//   Inner loop unrolled x4 with 8 independent min-chains (4 per src point)
//   -> 4 outstanding ds_read_b128 + no serial dependence (round-1 was
//   ~171 cyc/iter = single-outstanding LDS latency + serial min chain).
// Blocks [384,400): occlusion + static-flow + trafo-cycle losses, spread
//   across 4096 threads (round-1 single-block version cost ~65 us).
// out[0] zero-initialized by a captured hipMemsetAsync; one atomicAdd/block.
// ---------------------------------------------------------------------------
__global__ __launch_bounds__(256, 4) void fused_kernel(
    const float* __restrict__ pc0, const float* __restrict__ pc1,
    const float* __restrict__ flows_fw, const float* __restrict__ flows_bw,
    const float* __restrict__ disap_fw, const float* __restrict__ disap_bw,
    const float* __restrict__ trafo_fw, const float* __restrict__ trafo_bw,
    const float* __restrict__ stat_fw, const float* __restrict__ stat_bw,
    float* __restrict__ out)
{
    __shared__ float4 s_tgt[MM];      // 32 KB
    __shared__ float  s_bd[64][8];
    __shared__ int    s_bi[64][8];
    __shared__ float  s_red[4];

    int tid = threadIdx.x;
    int bid = blockIdx.x;

    if (bid < KNN_BLOCKS) {
        int chunk = bid & 31;
        int rest  = bid >> 5;
        int b = rest & 1; rest >>= 1;
        int t = rest % 3, dir = rest / 3;

        const float* pc_src = dir ? pc1 : pc0;
        const float* pc_tgt = dir ? pc0 : pc1;
        const float* fl_src = dir ? flows_bw : flows_fw;
        const float* fl_tgt = dir ? flows_fw : flows_bw;

        // Stage target cloud (24 KB from L2/L3) as padded float4.
        for (int p = tid; p < MM; p += 256) {
            const float* q = pc_tgt + ((size_t)b * MM + p) * 3;
            s_tgt[p] = make_float4(q[0], q[1], q[2], 0.f);
        }
        __syncthreads();

        int si = tid & 31, j = tid >> 5;
        int nA = chunk * 64 + si;                 // src point A; B = A+32

        const float* psA = pc_src + ((size_t)b * NN + nA) * 3;
        const float* fsA = fl_src + (((size_t)t * BB + b) * NN + nA) * 3;
        float wAx = psA[0] + fsA[0], wAy = psA[1] + fsA[1], wAz = psA[2] + fsA[2];
        const float* psB = psA + 32 * 3;
        const float* fsB = fsA + 32 * 3;
        float wBx = psB[0] + fsB[0], wBy = psB[1] + fsB[1], wBz = psB[2] + fsB[2];

        float bdA0 = INFF, bdA1 = INFF, bdA2 = INFF, bdA3 = INFF;
        float bdB0 = INFF, bdB1 = INFF, bdB2 = INFF, bdB3 = INFF;
        int   biA0 = 0, biA1 = 0, biA2 = 0, biA3 = 0;
        int   biB0 = 0, biB1 = 0, biB2 = 0, biB3 = 0;

        int m0 = j * 256;
        for (int mm = 0; mm < 256; mm += 4) {
            int m = m0 + mm;
            float4 t0 = s_tgt[m + 0];
            float4 t1 = s_tgt[m + 1];
            float4 t2 = s_tgt[m + 2];
            float4 t3 = s_tgt[m + 3];
            // strict < keeps first occurrence within each chain (ascending m)
            { float dx = wAx - t0.x, dy = wAy - t0.y, dz = wAz - t0.z;
              float d = dx*dx + dy*dy + dz*dz; if (d < bdA0) { bdA0 = d; biA0 = m + 0; } }
            { float dx = wBx - t0.x, dy = wBy - t0.y, dz = wBz - t0.z;
              float d = dx*dx + dy*dy + dz*dz; if (d < bdB0) { bdB0 = d; biB0 = m + 0; } }
            { float dx = wAx - t1.x, dy = wAy - t1.y, dz = wAz - t1.z;
              float d = dx*dx + dy*dy + dz*dz; if (d < bdA1) { bdA1 = d; biA1 = m + 1; } }
            { float dx = wBx - t1.x, dy = wBy - t1.y, dz = wBz - t1.z;
              float d = dx*dx + dy*dy + dz*dz; if (d < bdB1) { bdB1 = d; biB1 = m + 1; } }
            { float dx = wAx - t2.x, dy = wAy - t2.y, dz = wAz - t2.z;
              float d = dx*dx + dy*dy + dz*dz; if (d < bdA2) { bdA2 = d; biA2 = m + 2; } }
            { float dx = wBx - t2.x, dy = wBy - t2.y, dz = wBz - t2.z;
              float d = dx*dx + dy*dy + dz*dz; if (d < bdB2) { bdB2 = d; biB2 = m + 2; } }
            { float dx = wAx - t3.x, dy = wAy - t3.y, dz = wAz - t3.z;
              float d = dx*dx + dy*dy + dz*dz; if (d < bdA3) { bdA3 = d; biA3 = m + 3; } }
            { float dx = wBx - t3.x, dy = wBy - t3.y, dz = wBz - t3.z;
              float d = dx*dx + dy*dy + dz*dz; if (d < bdB3) { bdB3 = d; biB3 = m + 3; } }
        }

        // Merge the 4 chains per point; tie -> lowest index (matches argmin).
        float bA = bdA0; int iA = biA0;
        if (bdA1 < bA || (bdA1 == bA && biA1 < iA)) { bA = bdA1; iA = biA1; }
        if (bdA2 < bA || (bdA2 == bA && biA2 < iA)) { bA = bdA2; iA = biA2; }
        if (bdA3 < bA || (bdA3 == bA && biA3 < iA)) { bA = bdA3; iA = biA3; }
        float bB = bdB0; int iB = biB0;
        if (bdB1 < bB || (bdB1 == bB && biB1 < iB)) { bB = bdB1; iB = biB1; }
        if (bdB2 < bB || (bdB2 == bB && biB2 < iB)) { bB = bdB2; iB = biB2; }
        if (bdB3 < bB || (bdB3 == bB && biB3 < iB)) { bB = bdB3; iB = biB3; }

        s_bd[si][j]      = bA;  s_bi[si][j]      = iA;
        s_bd[si + 32][j] = bB;  s_bi[si + 32][j] = iB;
        __syncthreads();

        if (tid < 64) {          // wave 0: one src point each
            int n = chunk * 64 + tid;
            float best = s_bd[tid][0]; int bix = s_bi[tid][0];
            #pragma unroll
            for (int jj = 1; jj < 8; ++jj) {
                float d = s_bd[tid][jj]; int ii = s_bi[tid][jj];
                if (d < best || (d == best && ii < bix)) { best = d; bix = ii; }
            }
            const float* fs = fl_src + (((size_t)t * BB + b) * NN + n) * 3;   // L1-hot
            const float* pf = fl_tgt + (((size_t)t * BB + b) * MM + bix) * 3; // scattered, L2
            float ox = fs[0] + pf[0], oy = fs[1] + pf[1], oz = fs[2] + pf[2];

            const float scale = 0.5f / (BB * NN);
            float wnd = scale * (t == 0 ? 1.0f : 0.5f);   // KNN=1, DYN=STAT=0.5
            float wop = (t == 0 ? scale : 0.0f);          // OPP=1, aggregated only
            float contrib = wnd * best + wop * (ox * ox + oy * oy + oz * oz);

            #pragma unroll
            for (int off = 32; off; off >>= 1)
                contrib += __shfl_down(contrib, off, 64);
            if (tid == 0) atomicAdd(out, contrib);
        }
    } else {
        // ------------------ aux losses, spread over 4096 threads -----------
        int r = (bid - KNN_BLOCKS) * 256 + tid;   // 0..4095 = b*N+n
        int b = r >> 11;
        const float occl_w = 0.1f * 0.5f / (BB * NN);
        const float sf_w   = 0.5f / (BB * NN);

        float acc = 0.f;
        #pragma unroll
        for (int d = 0; d < 2; ++d) {
            const float* disap = d ? disap_bw : disap_fw;
            const float* pc    = d ? pc1 : pc0;
            const float* fl    = (d ? flows_bw : flows_fw)
                                 + (size_t)2 * BB * NN * 3 + (size_t)r * 3;  // flows[2]
            const float* st    = d ? stat_bw : stat_fw;
            const float* Tm    = (d ? trafo_bw : trafo_fw) + b * 16;

            acc += occl_w * disap[r];
            float x = pc[r * 3 + 0], y = pc[r * 3 + 1], z = pc[r * 3 + 2];
            float i0 = Tm[0]*x + Tm[1]*y + Tm[2] *z + Tm[3]  - x;
            float i1 = Tm[4]*x + Tm[5]*y + Tm[6] *z + Tm[7]  - y;
            float i2 = Tm[8]*x + Tm[9]*y + Tm[10]*z + Tm[11] - z;
            float d0 = fl[0] - i0, d1 = fl[1] - i1, d2 = fl[2] - i2;
            acc += sf_w * st[r] * (d0*d0 + d1*d1 + d2*d2);
        }

        // trafo cycle loss (32 entries), block 384 only
        if (bid == KNN_BLOCKS && tid < 32) {
            int bb = tid >> 4, i = (tid >> 2) & 3, k = tid & 3;
            float v = 0.f;
            #pragma unroll
            for (int jj = 0; jj < 4; ++jj)
                v += trafo_fw[bb * 16 + i * 4 + jj] * trafo_bw[bb * 16 + jj * 4 + k];
            v -= (i == k) ? 1.f : 0.f;
            acc += v * v * (1.0f / BB);
        }

        #pragma unroll
        for (int off = 32; off; off >>= 1)
            acc += __shfl_down(acc, off, 64);
        if ((tid & 63) == 0) s_red[tid >> 6] = acc;
        __syncthreads();
        if (tid == 0) atomicAdd(out, s_red[0] + s_red[1] + s_red[2] + s_red[3]);
    }
}

extern "C" void kernel_launch(void* const* d_in, const int* in_sizes, int n_in,
                              void* d_out, int out_size, void* d_ws, size_t ws_size,
                              hipStream_t stream) {
    const float* pc0      = (const float*)d_in[0];
    const float* pc1      = (const float*)d_in[1];
    const float* flows_fw = (const float*)d_in[2];
    const float* flows_bw = (const float*)d_in[3];
    const float* disap_fw = (const float*)d_in[4];
    const float* disap_bw = (const float*)d_in[5];
    const float* trafo_fw = (const float*)d_in[6];
    const float* trafo_bw = (const float*)d_in[7];
    const float* stat_fw  = (const float*)d_in[8];
    const float* stat_bw  = (const float*)d_in[9];
    float* out = (float*)d_out;

    // Zero the accumulator (d_out is poisoned to 0xAA before every launch).
    // hipMemsetAsync on the capture stream becomes a graph memset node.
    hipMemsetAsync(out, 0, sizeof(float), stream);

    fused_kernel<<<KNN_BLOCKS + AUX_BLOCKS, 256, 0, stream>>>(
        pc0, pc1, flows_fw, flows_bw, disap_fw, disap_bw,
        trafo_fw, trafo_bw, stat_fw, stat_bw, out);
}

// Round 3
// 83.651 us; speedup vs baseline: 1.5694x; 1.1018x over previous
//
#include <hip/hip_runtime.h>

// Problem constants: B=2, N=M=2048, T=3 flow types.
#define TT 3
#define BB 2
#define NN 2048
#define MM 2048
#define KNN_BLOCKS 768   // 2(dir) * 3(t) * 2(b) * 64 chunks of 32 src = 3 blocks/CU exactly
#define CH_PAD 65        // padded chunk stride (float4 units): 8 wave-broadcast addrs -> 8 distinct bank-quads
#define INFF 3.402823466e38f

// ---------------------------------------------------------------------------
// Kernel 1: NN chamfer (+ opposite-flow for t=0) + distributed aux losses.
// Design notes (R2 post-mortem): R2 ran 1.5 waves/SIMD -> LDS latency exposed
// (~178 cyc/read). This version: 768 blocks = 3/CU co-resident (12 waves/CU),
// dot-product form c = h - w.t with h=|t|^2/2 staged in .w (4 VALU/pair for
// t=1,2 which need no argmin; 6 for t=0), P=4 src per LDS read.
// Each block plain-stores its partial to ws[bid]  (no atomics, no memset).
// ---------------------------------------------------------------------------
__global__ __launch_bounds__(256, 3) void knn_kernel(
    const float* __restrict__ pc0, const float* __restrict__ pc1,
    const float* __restrict__ flows_fw, const float* __restrict__ flows_bw,
    const float* __restrict__ disap_fw, const float* __restrict__ disap_bw,
    const float* __restrict__ trafo_fw, const float* __restrict__ trafo_bw,
    const float* __restrict__ stat_fw, const float* __restrict__ stat_bw,
    float* __restrict__ ws)
{
    __shared__ float4 s_tgt[32 * CH_PAD];   // 33,280 B
    __shared__ float  s_bd[32][33];         // +1 pad: merge reads conflict-free
    __shared__ int    s_bi[32][33];
    __shared__ float  s_w2[32];
    __shared__ float  s_red[4];

    int tid = threadIdx.x;
    int bid = blockIdx.x;

    int chunk = bid & 63;          // 64 chunks of 32 src points
    int rest  = bid >> 6;
    int b = rest & 1; rest >>= 1;
    int t = rest % 3, dir = rest / 3;

    const float* pc_src = dir ? pc1 : pc0;
    const float* pc_tgt = dir ? pc0 : pc1;
    const float* fl_src = dir ? flows_bw : flows_fw;
    const float* fl_tgt = dir ? flows_fw : flows_bw;

    // ---- stage targets: {x,y,z, |t|^2/2}, chunk-padded layout ----
    for (int p = tid; p < MM; p += 256) {
        const float* q = pc_tgt + ((size_t)b * MM + p) * 3;
        float x = q[0], y = q[1], z = q[2];
        float h = 0.5f * (x * x + y * y + z * z);
        s_tgt[(p >> 6) * CH_PAD + (p & 63)] = make_float4(x, y, z, h);
    }

    // ---- per-thread sources: P=4, sl = tid&7, j = tid>>3 (target chunk) ----
    int sl = tid & 7, j = tid >> 3;
    float nwx[4], nwy[4], nwz[4];
    #pragma unroll
    for (int k = 0; k < 4; ++k) {
        int n = chunk * 32 + sl + 8 * k;
        const float* ps = pc_src + ((size_t)b * NN + n) * 3;
        const float* fs = fl_src + (((size_t)t * BB + b) * NN + n) * 3;
        float wx = ps[0] + fs[0], wy = ps[1] + fs[1], wz = ps[2] + fs[2];
        nwx[k] = -wx; nwy[k] = -wy; nwz[k] = -wz;
        if (j == 0) s_w2[sl + 8 * k] = wx * wx + wy * wy + wz * wz;
    }
    __syncthreads();

    const float4* tp = s_tgt + j * CH_PAD;   // this thread's 64-target chunk

    if (t != 0) {
        // ---- min-only path: 3 FMA + 1 min per pair, 16 chains ----
        float bd[4][4];
        #pragma unroll
        for (int k = 0; k < 4; ++k)
            #pragma unroll
            for (int u = 0; u < 4; ++u) bd[k][u] = INFF;
        for (int i = 0; i < 64; i += 4) {
            float4 T0 = tp[i], T1 = tp[i + 1], T2 = tp[i + 2], T3 = tp[i + 3];
            #pragma unroll
            for (int k = 0; k < 4; ++k) {
                float c0 = fmaf(nwx[k], T0.x, fmaf(nwy[k], T0.y, fmaf(nwz[k], T0.z, T0.w)));
                float c1 = fmaf(nwx[k], T1.x, fmaf(nwy[k], T1.y, fmaf(nwz[k], T1.z, T1.w)));
                float c2 = fmaf(nwx[k], T2.x, fmaf(nwy[k], T2.y, fmaf(nwz[k], T2.z, T2.w)));
                float c3 = fmaf(nwx[k], T3.x, fmaf(nwy[k], T3.y, fmaf(nwz[k], T3.z, T3.w)));
                bd[k][0] = fminf(bd[k][0], c0);
                bd[k][1] = fminf(bd[k][1], c1);
                bd[k][2] = fminf(bd[k][2], c2);
                bd[k][3] = fminf(bd[k][3], c3);
            }
        }
        #pragma unroll
        for (int k = 0; k < 4; ++k)
            s_bd[sl + 8 * k][j] = fminf(fminf(bd[k][0], bd[k][1]), fminf(bd[k][2], bd[k][3]));
    } else {
        // ---- argmin path (opp loss needs partner index), 8 chains ----
        float bd[4][2]; int bi[4][2];
        #pragma unroll
        for (int k = 0; k < 4; ++k) {
            bd[k][0] = INFF; bd[k][1] = INFF; bi[k][0] = 0; bi[k][1] = 0;
        }
        int jbase = j * 64;
        for (int i = 0; i < 64; i += 2) {
            float4 T0 = tp[i], T1 = tp[i + 1];
            int m0 = jbase + i, m1 = m0 + 1;
            #pragma unroll
            for (int k = 0; k < 4; ++k) {
                float c0 = fmaf(nwx[k], T0.x, fmaf(nwy[k], T0.y, fmaf(nwz[k], T0.z, T0.w)));
                float c1 = fmaf(nwx[k], T1.x, fmaf(nwy[k], T1.y, fmaf(nwz[k], T1.z, T1.w)));
                if (c0 < bd[k][0]) { bd[k][0] = c0; bi[k][0] = m0; }  // strict <: first occurrence
                if (c1 < bd[k][1]) { bd[k][1] = c1; bi[k][1] = m1; }
            }
        }
        #pragma unroll
        for (int k = 0; k < 4; ++k) {
            float d0 = bd[k][0], d1 = bd[k][1];
            int   i0 = bi[k][0], i1 = bi[k][1];
            bool take1 = (d1 < d0) || (d1 == d0 && i1 < i0);  // tie -> lower index
            s_bd[sl + 8 * k][j] = take1 ? d1 : d0;
            s_bi[sl + 8 * k][j] = take1 ? i1 : i0;
        }
    }
    __syncthreads();

    // ---- final merge (threads 0..31, one src each) + aux, block reduce ----
    float contrib = 0.f;
    if (tid < 32) {
        int n = chunk * 32 + tid;
        if (t == 0) {
            float best = s_bd[tid][0]; int bix = s_bi[tid][0];
            #pragma unroll 4
            for (int jj = 1; jj < 32; ++jj) {
                float d = s_bd[tid][jj]; int ii = s_bi[tid][jj];
                if (d < best) { best = d; bix = ii; }   // ascending jj => ascending idx ranges
            }
            float nd2 = fmaxf(fmaf(2.f, best, s_w2[tid]), 0.f);
            const float* fs = fl_src + ((size_t)b * NN + n) * 3;           // t=0 slab
            const float* pf = fl_tgt + ((size_t)b * MM + bix) * 3;
            float ox = fs[0] + pf[0], oy = fs[1] + pf[1], oz = fs[2] + pf[2];
            const float sc = 0.5f / (BB * NN);   // KNN_PEN and OPP_PEN both 1
            contrib = sc * (nd2 + ox * ox + oy * oy + oz * oz);
        } else {
            float best = s_bd[tid][0];
            #pragma unroll 4
            for (int jj = 1; jj < 32; ++jj) best = fminf(best, s_bd[tid][jj]);
            float nd2 = fmaxf(fmaf(2.f, best, s_w2[tid]), 0.f);
            contrib = (0.25f / (BB * NN)) * nd2;  // DYN/STAT_PEN=0.5 * 0.5/(B*N)
        }
    }

    // aux losses: blocks 0..31 cover all 8192 items, 1 per thread
    int aidx = bid * 256 + tid;
    if (aidx < 2 * BB * NN) {
        int d  = aidx >> 12;              // 0 fw / 1 bw
        int r  = aidx & (BB * NN - 1);
        int rb = r >> 11;
        const float* disap = d ? disap_bw : disap_fw;
        const float* pcx   = d ? pc1 : pc0;
        const float* fl    = (d ? flows_bw : flows_fw) + (size_t)2 * BB * NN * 3 + (size_t)r * 3;
        const float* st    = d ? stat_bw : stat_fw;
        const float* Tm    = (d ? trafo_bw : trafo_fw) + rb * 16;
        contrib += (0.05f / (BB * NN)) * disap[r];       // OCCL_PEN*0.5/(B*N)
        float x = pcx[r * 3], y = pcx[r * 3 + 1], z = pcx[r * 3 + 2];
        float i0 = Tm[0] * x + Tm[1] * y + Tm[2]  * z + Tm[3]  - x;
        float i1 = Tm[4] * x + Tm[5] * y + Tm[6]  * z + Tm[7]  - y;
        float i2 = Tm[8] * x + Tm[9] * y + Tm[10] * z + Tm[11] - z;
        float e0 = fl[0] - i0, e1 = fl[1] - i1, e2 = fl[2] - i2;
        contrib += (0.5f / (BB * NN)) * st[r] * (e0 * e0 + e1 * e1 + e2 * e2);
    }

    #pragma unroll
    for (int off = 32; off; off >>= 1)
        contrib += __shfl_down(contrib, off, 64);
    if ((tid & 63) == 0) s_red[tid >> 6] = contrib;
    __syncthreads();
    if (tid == 0) ws[bid] = s_red[0] + s_red[1] + s_red[2] + s_red[3];
}

// ---------------------------------------------------------------------------
// Kernel 2: reduce 768 block partials + trafo-cycle loss; plain-store out[0].
// Stream order guarantees kernel1's ws writes are visible.
// ---------------------------------------------------------------------------
__global__ __launch_bounds__(256) void reduce_kernel(
    const float* __restrict__ ws,
    const float* __restrict__ trafo_fw, const float* __restrict__ trafo_bw,
    float* __restrict__ out)
{
    __shared__ float s_red[4];
    int tid = threadIdx.x;
    float acc = ws[tid] + ws[tid + 256] + ws[tid + 512];

    if (tid < 32) {   // trafo cycle: mean_b ||T_fw T_bw - I||_F^2
        int bb = tid >> 4, i = (tid >> 2) & 3, k = tid & 3;
        float v = -((i == k) ? 1.f : 0.f);
        #pragma unroll
        for (int jj = 0; jj < 4; ++jj)
            v += trafo_fw[bb * 16 + i * 4 + jj] * trafo_bw[bb * 16 + jj * 4 + k];
        acc += v * v * (1.0f / BB);
    }

    #pragma unroll
    for (int off = 32; off; off >>= 1)
        acc += __shfl_down(acc, off, 64);
    if ((tid & 63) == 0) s_red[tid >> 6] = acc;
    __syncthreads();
    if (tid == 0) out[0] = s_red[0] + s_red[1] + s_red[2] + s_red[3];
}

extern "C" void kernel_launch(void* const* d_in, const int* in_sizes, int n_in,
                              void* d_out, int out_size, void* d_ws, size_t ws_size,
                              hipStream_t stream) {
    const float* pc0      = (const float*)d_in[0];
    const float* pc1      = (const float*)d_in[1];
    const float* flows_fw = (const float*)d_in[2];
    const float* flows_bw = (const float*)d_in[3];
    const float* disap_fw = (const float*)d_in[4];
    const float* disap_bw = (const float*)d_in[5];
    const float* trafo_fw = (const float*)d_in[6];
    const float* trafo_bw = (const float*)d_in[7];
    const float* stat_fw  = (const float*)d_in[8];
    const float* stat_bw  = (const float*)d_in[9];
    float* out = (float*)d_out;
    float* ws  = (float*)d_ws;

    knn_kernel<<<KNN_BLOCKS, 256, 0, stream>>>(
        pc0, pc1, flows_fw, flows_bw, disap_fw, disap_bw,
        trafo_fw, trafo_bw, stat_fw, stat_bw, ws);
    reduce_kernel<<<1, 256, 0, stream>>>(ws, trafo_fw, trafo_bw, out);
}